// Round 12
// baseline (87.332 us; speedup 1.0000x reference)
//
#include <hip/hip_runtime.h>
#include <hip/hip_bf16.h>

#define FDIM 128
#define NLEV 4
#define NT   64     // nodes per transform block (R10 showed NT=128 regresses)
#define WPAD 136    // padded row stride (u16): 272B -> 2-way bank alias (free)
#define SLOTS 8     // ELL width; deg>SLOTS goes to overflow list
#define OVFCAP 65536

typedef unsigned int  u32;
typedef unsigned short u16;

typedef __attribute__((ext_vector_type(8))) short short8v;  // 8 bf16 (4 VGPRs)
typedef __attribute__((ext_vector_type(4))) float f32x4;    // clang vector: ok for nontemporal builtins

__device__ __forceinline__ float bf_lo(u32 p) { return __uint_as_float(p << 16); }
__device__ __forceinline__ float bf_hi(u32 p) { return __uint_as_float(p & 0xffff0000u); }
__device__ __forceinline__ u16 f2bf(float f) {
    u32 u = __float_as_uint(f);
    u32 r = (u + 0x7fffu + ((u >> 16) & 1u)) >> 16;   // round-nearest-even
    return (u16)r;
}
__device__ __forceinline__ u32 pack2(float a, float b) {
    return (u32)f2bf(a) | ((u32)f2bf(b) << 16);
}

// ---- K0: fast zero (grid-stride int4) ----
__global__ __launch_bounds__(256) void zero_kernel(int4* __restrict__ p, int n4) {
    int i = blockIdx.x * 256 + threadIdx.x;
    int stride = gridDim.x * 256;
    for (; i < n4; i += stride) p[i] = make_int4(0, 0, 0, 0);
}

// ---- K1: single edge pass (2 edges/thread, int4 loads) builds ELL directly,
//          plus node-binning role on the first nodeBlocks blocks ----
__global__ __launch_bounds__(256) void fillbin_kernel(
    const int* __restrict__ lv, int* __restrict__ cnt, int* __restrict__ bin,
    const int4* __restrict__ edges4, int* __restrict__ deg, int* __restrict__ ell,
    int2* __restrict__ ovf, int* __restrict__ ovfcnt,
    int N, int E, int nodeBlocks)
{
    int t = threadIdx.x;
    int b = blockIdx.x;

    int e2 = b * 256 + t;            // pair index: edges 2*e2, 2*e2+1
    if (2 * e2 + 1 < E) {
        int4 ed = edges4[e2];
        if (lv[ed.y] > lv[ed.x]) {
            int slot = atomicAdd(&deg[ed.y], 1);
            if (slot < SLOTS) ell[ed.y * SLOTS + slot] = ed.x;
            else { int oi = atomicAdd(ovfcnt, 1); if (oi < OVFCAP) ovf[oi] = make_int2(ed.x, ed.y); }
        }
        if (lv[ed.w] > lv[ed.z]) {
            int slot = atomicAdd(&deg[ed.w], 1);
            if (slot < SLOTS) ell[ed.w * SLOTS + slot] = ed.z;
            else { int oi = atomicAdd(ovfcnt, 1); if (oi < OVFCAP) ovf[oi] = make_int2(ed.z, ed.w); }
        }
    } else if (2 * e2 == E - 1) {    // odd-E tail
        const int2* edges2 = (const int2*)edges4;
        int2 ed = edges2[E - 1];
        if (lv[ed.y] > lv[ed.x]) {
            int slot = atomicAdd(&deg[ed.y], 1);
            if (slot < SLOTS) ell[ed.y * SLOTS + slot] = ed.x;
            else { int oi = atomicAdd(ovfcnt, 1); if (oi < OVFCAP) ovf[oi] = make_int2(ed.x, ed.y); }
        }
    }

    if (b < nodeBlocks) {
        __shared__ int lcnt[NLEV];
        __shared__ int lbase[NLEV];
        if (t < NLEV) lcnt[t] = 0;
        __syncthreads();
        int n = b * 256 + t;
        int l = -1, pos = 0;
        if (n < N) {
            l = lv[n];
            if (l >= 0 && l < NLEV) pos = atomicAdd(&lcnt[l], 1);
            else l = -1;
        }
        __syncthreads();
        if (t < NLEV) lbase[t] = lcnt[t] ? atomicAdd(&cnt[t], lcnt[t]) : 0;
        __syncthreads();
        if (l >= 0) bin[l * N + lbase[l] + pos] = n;
    }
}

// ---- K2 (MFMA): Y[n] = bf16( 0.2*(X[n] @ W[l].T + b[l]) ), NT=64 nodes/block ----
// LDS: single Wt buffer (35KB), rows 0..63 reused as output staging -> 4 blocks/CU.
__global__ __launch_bounds__(256) void transform_kernel(
    const float* __restrict__ X, const float* __restrict__ Wg,
    const float* __restrict__ bg, const int* __restrict__ cnt,
    const int* __restrict__ bin, u16* __restrict__ Y, int N, int blocksPerLevel)
{
    __shared__ __align__(16) u16 Wt[FDIM][WPAD];
    __shared__ int nodes_s[NT];

    int b = blockIdx.x;
    int l     = b / blocksPerLevel;
    int chunk = b % blocksPerLevel;
    int m_total = cnt[l];
    int base = chunk * NT;
    if (base >= m_total) return;
    int m = min(NT, m_total - base);
    int t = threadIdx.x;

    if (t < NT) nodes_s[t] = (t < m) ? bin[l * N + base + t] : -1;

    const float4* Wl4 = (const float4*)(Wg + (size_t)l * FDIM * FDIM);
    #pragma unroll
    for (int k = 0; k < 16; ++k) {
        int flat4 = t + k * 256;
        int row = flat4 >> 5;
        int c4  = flat4 & 31;
        float4 v = Wl4[flat4];
        *(uint2*)&Wt[row][c4 * 4] = make_uint2(pack2(v.x, v.y), pack2(v.z, v.w));
    }
    __syncthreads();

    int wid  = t >> 6;
    int lane = t & 63;
    int arow = lane & 15;
    int kgrp = lane >> 4;

    int node = nodes_s[wid * 16 + arow];
    const float* xrow = X + (size_t)(node < 0 ? 0 : node) * FDIM;

    f32x4 acc[8];
    #pragma unroll
    for (int ft = 0; ft < 8; ++ft) acc[ft] = (f32x4){0.f, 0.f, 0.f, 0.f};

    #pragma unroll
    for (int kstep = 0; kstep < 4; ++kstep) {
        int k0 = kstep * 32 + kgrp * 8;
        union { u32 u[4]; short8v v; } au;
        if (node >= 0) {
            float4 x0 = *(const float4*)&xrow[k0];
            float4 x1 = *(const float4*)&xrow[k0 + 4];
            au.u[0] = pack2(x0.x, x0.y); au.u[1] = pack2(x0.z, x0.w);
            au.u[2] = pack2(x1.x, x1.y); au.u[3] = pack2(x1.z, x1.w);
        } else {
            au.u[0] = au.u[1] = au.u[2] = au.u[3] = 0;
        }
        #pragma unroll
        for (int ft = 0; ft < 8; ++ft) {
            short8v bb = *(const short8v*)&Wt[ft * 16 + arow][k0];
            acc[ft] = __builtin_amdgcn_mfma_f32_16x16x32_bf16(au.v, bb, acc[ft], 0, 0, 0);
        }
    }

    __syncthreads();   // all waves done reading Wt -> safe to overwrite rows 0..63

    const float* bl = bg + l * FDIM;
    #pragma unroll
    for (int ft = 0; ft < 8; ++ft) {
        float bv = bl[ft * 16 + arow];
        #pragma unroll
        for (int reg = 0; reg < 4; ++reg) {
            int r = wid * 16 + kgrp * 4 + reg;       // this wave's own rows only
            Wt[r][ft * 16 + arow] = f2bf(0.2f * (acc[ft][reg] + bv));
        }
    }
    __syncthreads();

    #pragma unroll
    for (int k = 0; k < 4; ++k) {
        int flat16 = t + k * 256;
        int row = flat16 >> 4;
        int c   = flat16 & 15;
        int nd = nodes_s[row];
        if (nd >= 0)
            *(uint4*)&Y[(size_t)nd * FDIM + c * 8] = *(const uint4*)&Wt[row][c * 8];
    }
}

// ---- K3: gather from ELL. Half-wave per node; broadcast ELL row, burst Y loads.
//      out is write-once -> nontemporal store; X is last-use -> nontemporal load.
__global__ __launch_bounds__(256) void gather_kernel(
    const float* __restrict__ X, const uint2* __restrict__ Yp,
    const int* __restrict__ deg, const int4* __restrict__ ell4,
    float* __restrict__ out, int N)
{
    int wid  = threadIdx.x >> 6;
    int lane = threadIdx.x & 63;
    int hl = lane >> 5;          // half: 0 or 1
    int sl = lane & 31;          // sub-lane within half
    int node = blockIdx.x * 8 + wid * 2 + hl;
    if (node >= N) return;

    f32x4 xv = __builtin_nontemporal_load((const f32x4*)&X[(size_t)node * FDIM + sl * 4]);
    int4 e0 = ell4[node * 2];        // slots 0..3 (same addr across 32 lanes: L1 broadcast)
    int4 e1 = ell4[node * 2 + 1];    // slots 4..7
    int d = deg[node];
    if (d > SLOTS) d = SLOTS;

    int slots[SLOTS] = { e0.x, e0.y, e0.z, e0.w, e1.x, e1.y, e1.z, e1.w };

    uint2 p[SLOTS];
    #pragma unroll
    for (int j = 0; j < SLOTS; ++j)
        if (j < d) p[j] = Yp[(size_t)slots[j] * (FDIM / 4) + sl];   // 8B/lane, 256B/edge

    float a0 = 0.f, a1 = 0.f, a2 = 0.f, a3 = 0.f;
    #pragma unroll
    for (int j = 0; j < SLOTS; ++j) {
        if (j < d) {
            a0 += bf_lo(p[j].x); a1 += bf_hi(p[j].x);
            a2 += bf_lo(p[j].y); a3 += bf_hi(p[j].y);
        }
    }
    f32x4 o = { xv.x + a0, xv.y + a1, xv.z + a2, xv.w + a3 };
    __builtin_nontemporal_store(o, (f32x4*)&out[(size_t)node * FDIM + sl * 4]);
}

// ---- K4: replay overflow edges (deg > SLOTS) with f32 atomics; tiny count ----
__global__ __launch_bounds__(256) void ovf_kernel(
    const int2* __restrict__ ovf, const int* __restrict__ ovfcnt,
    const uint2* __restrict__ Yp, float* __restrict__ out)
{
    int cnt = *ovfcnt;
    if (cnt > OVFCAP) cnt = OVFCAP;
    int hw  = (blockIdx.x * 256 + threadIdx.x) >> 5;   // global half-wave id
    int sl  = threadIdx.x & 31;
    int nhw = gridDim.x * 8;
    for (int i = hw; i < cnt; i += nhw) {
        int2 ed = ovf[i];
        uint2 pv = Yp[(size_t)ed.x * (FDIM / 4) + sl];
        float* dst = out + (size_t)ed.y * FDIM + sl * 4;
        atomicAdd(dst + 0, bf_lo(pv.x));
        atomicAdd(dst + 1, bf_hi(pv.x));
        atomicAdd(dst + 2, bf_lo(pv.y));
        atomicAdd(dst + 3, bf_hi(pv.y));
    }
}

extern "C" void kernel_launch(void* const* d_in, const int* in_sizes, int n_in,
                              void* d_out, int out_size, void* d_ws, size_t ws_size,
                              hipStream_t stream) {
    const float* X  = (const float*)d_in[0];
    const float* Wg = (const float*)d_in[1];
    const float* bg = (const float*)d_in[2];
    const int*   lv = (const int*)d_in[3];
    const int*   eg = (const int*)d_in[4];
    float* out = (float*)d_out;

    int N = in_sizes[3];
    int E = in_sizes[4] / 2;

    // workspace: Y (bf16 N*F) | cnt(16: [0..3] level counts, [8] ovf counter)
    //            deg(N) [zeroed with cnt] | ell(8N) | bin(4N) | ovf(OVFCAP int2)
    char* p = (char*)d_ws;
    u16* Y     = (u16*)p;   p += (size_t)N * FDIM * sizeof(u16);
    int* cnt   = (int*)p;   p += 16 * sizeof(int);
    int* deg   = (int*)p;   p += (size_t)N * sizeof(int);
    int* ell   = (int*)p;   p += (size_t)SLOTS * N * sizeof(int);
    int* bin   = (int*)p;   p += (size_t)4 * N * sizeof(int);
    int2* ovf  = (int2*)p;
    int* ovfcnt = cnt + 8;

    int nzero4 = (N + 16) / 4;   // cnt(16) + deg(N), N divisible by 4
    zero_kernel<<<(nzero4 + 255) / 256, 256, 0, stream>>>((int4*)cnt, nzero4);

    int nodeBlocks  = (N + 255) / 256;
    int edgeBlocks2 = ((E + 1) / 2 + 255) / 256;   // 2 edges per thread
    fillbin_kernel<<<max(nodeBlocks, edgeBlocks2), 256, 0, stream>>>(
        lv, cnt, bin, (const int4*)eg, deg, ell, ovf, ovfcnt, N, E, nodeBlocks);

    int blocksPerLevel = (N + NT - 1) / NT;
    transform_kernel<<<NLEV * blocksPerLevel, 256, 0, stream>>>(
        X, Wg, bg, cnt, bin, Y, N, blocksPerLevel);

    gather_kernel<<<(N + 7) / 8, 256, 0, stream>>>(
        X, (const uint2*)Y, deg, (const int4*)ell, out, N);

    ovf_kernel<<<64, 256, 0, stream>>>(ovf, ovfcnt, (const uint2*)Y, out);
}

// Round 13
// 79.248 us; speedup vs baseline: 1.1020x; 1.1020x over previous
//
#include <hip/hip_runtime.h>
#include <hip/hip_bf16.h>

#define FDIM 128
#define NLEV 4
#define NT   64     // nodes per transform block
#define WPAD 136    // padded row stride (u16): 272B -> 2-way bank alias (free)
#define SLOTS 8     // ELL width; deg>SLOTS goes to overflow list
#define OVFCAP 65536

typedef unsigned int  u32;
typedef unsigned short u16;

typedef __attribute__((ext_vector_type(8))) short short8v;  // 8 bf16 (4 VGPRs)
typedef __attribute__((ext_vector_type(4))) float f32x4;

__device__ __forceinline__ float bf_lo(u32 p) { return __uint_as_float(p << 16); }
__device__ __forceinline__ float bf_hi(u32 p) { return __uint_as_float(p & 0xffff0000u); }
__device__ __forceinline__ u16 f2bf(float f) {
    u32 u = __float_as_uint(f);
    u32 r = (u + 0x7fffu + ((u >> 16) & 1u)) >> 16;   // round-nearest-even
    return (u16)r;
}
__device__ __forceinline__ u32 pack2(float a, float b) {
    return (u32)f2bf(a) | ((u32)f2bf(b) << 16);
}

// ---- K0: fast zero (grid-stride int4) ----
__global__ __launch_bounds__(256) void zero_kernel(int4* __restrict__ p, int n4) {
    int i = blockIdx.x * 256 + threadIdx.x;
    int stride = gridDim.x * 256;
    for (; i < n4; i += stride) p[i] = make_int4(0, 0, 0, 0);
}

// ---- K1: single edge pass builds ELL directly (deg doubles as slot cursor),
//          plus node-binning role on the first nodeBlocks blocks.
//          1 edge/thread: latency-bound atomics want max wave concurrency. ----
__global__ __launch_bounds__(256) void fillbin_kernel(
    const int* __restrict__ lv, int* __restrict__ cnt, int* __restrict__ bin,
    const int2* __restrict__ edges2, int* __restrict__ deg, int* __restrict__ ell,
    int2* __restrict__ ovf, int* __restrict__ ovfcnt,
    int N, int E, int nodeBlocks)
{
    int t = threadIdx.x;
    int b = blockIdx.x;

    int e = b * 256 + t;
    if (e < E) {
        int2 ed = edges2[e];
        int lo = ed.x, hi = ed.y;
        if (lv[hi] > lv[lo]) {                     // valid <=> lv[hi] > lv[lo]
            int slot = atomicAdd(&deg[hi], 1);
            if (slot < SLOTS) ell[hi * SLOTS + slot] = lo;
            else {
                int oi = atomicAdd(ovfcnt, 1);
                if (oi < OVFCAP) ovf[oi] = make_int2(lo, hi);
            }
        }
    }

    if (b < nodeBlocks) {
        __shared__ int lcnt[NLEV];
        __shared__ int lbase[NLEV];
        if (t < NLEV) lcnt[t] = 0;
        __syncthreads();
        int n = b * 256 + t;
        int l = -1, pos = 0;
        if (n < N) {
            l = lv[n];
            if (l >= 0 && l < NLEV) pos = atomicAdd(&lcnt[l], 1);
            else l = -1;
        }
        __syncthreads();
        if (t < NLEV) lbase[t] = lcnt[t] ? atomicAdd(&cnt[t], lcnt[t]) : 0;
        __syncthreads();
        if (l >= 0) bin[l * N + lbase[l] + pos] = n;
    }
}

// ---- K2 (MFMA): Y[n] = bf16( 0.2*(X[n] @ W[l].T + b[l]) ), NT=64 nodes/block ----
// LDS: single Wt buffer (35KB), rows 0..63 reused as output staging -> 4 blocks/CU.
__global__ __launch_bounds__(256) void transform_kernel(
    const float* __restrict__ X, const float* __restrict__ Wg,
    const float* __restrict__ bg, const int* __restrict__ cnt,
    const int* __restrict__ bin, u16* __restrict__ Y, int N, int blocksPerLevel)
{
    __shared__ __align__(16) u16 Wt[FDIM][WPAD];
    __shared__ int nodes_s[NT];

    int b = blockIdx.x;
    int l     = b / blocksPerLevel;
    int chunk = b % blocksPerLevel;
    int m_total = cnt[l];
    int base = chunk * NT;
    if (base >= m_total) return;
    int m = min(NT, m_total - base);
    int t = threadIdx.x;

    if (t < NT) nodes_s[t] = (t < m) ? bin[l * N + base + t] : -1;

    const float4* Wl4 = (const float4*)(Wg + (size_t)l * FDIM * FDIM);
    #pragma unroll
    for (int k = 0; k < 16; ++k) {
        int flat4 = t + k * 256;
        int row = flat4 >> 5;
        int c4  = flat4 & 31;
        float4 v = Wl4[flat4];
        *(uint2*)&Wt[row][c4 * 4] = make_uint2(pack2(v.x, v.y), pack2(v.z, v.w));
    }
    __syncthreads();

    int wid  = t >> 6;
    int lane = t & 63;
    int arow = lane & 15;
    int kgrp = lane >> 4;

    int node = nodes_s[wid * 16 + arow];
    const float* xrow = X + (size_t)(node < 0 ? 0 : node) * FDIM;

    f32x4 acc[8];
    #pragma unroll
    for (int ft = 0; ft < 8; ++ft) acc[ft] = (f32x4){0.f, 0.f, 0.f, 0.f};

    #pragma unroll
    for (int kstep = 0; kstep < 4; ++kstep) {
        int k0 = kstep * 32 + kgrp * 8;
        union { u32 u[4]; short8v v; } au;
        if (node >= 0) {
            float4 x0 = *(const float4*)&xrow[k0];
            float4 x1 = *(const float4*)&xrow[k0 + 4];
            au.u[0] = pack2(x0.x, x0.y); au.u[1] = pack2(x0.z, x0.w);
            au.u[2] = pack2(x1.x, x1.y); au.u[3] = pack2(x1.z, x1.w);
        } else {
            au.u[0] = au.u[1] = au.u[2] = au.u[3] = 0;
        }
        #pragma unroll
        for (int ft = 0; ft < 8; ++ft) {
            short8v bb = *(const short8v*)&Wt[ft * 16 + arow][k0];
            acc[ft] = __builtin_amdgcn_mfma_f32_16x16x32_bf16(au.v, bb, acc[ft], 0, 0, 0);
        }
    }

    __syncthreads();   // all waves done reading Wt -> safe to overwrite rows 0..63

    const float* bl = bg + l * FDIM;
    #pragma unroll
    for (int ft = 0; ft < 8; ++ft) {
        float bv = bl[ft * 16 + arow];
        #pragma unroll
        for (int reg = 0; reg < 4; ++reg) {
            int r = wid * 16 + kgrp * 4 + reg;       // this wave's own rows only
            Wt[r][ft * 16 + arow] = f2bf(0.2f * (acc[ft][reg] + bv));
        }
    }
    __syncthreads();

    #pragma unroll
    for (int k = 0; k < 4; ++k) {
        int flat16 = t + k * 256;
        int row = flat16 >> 4;
        int c   = flat16 & 15;
        int nd = nodes_s[row];
        if (nd >= 0)
            *(uint4*)&Y[(size_t)nd * FDIM + c * 8] = *(const uint4*)&Wt[row][c * 8];
    }
}

// ---- K3: gather from ELL. Half-wave per node; broadcast ELL row, burst Y loads ----
__global__ __launch_bounds__(256) void gather_kernel(
    const float* __restrict__ X, const uint2* __restrict__ Yp,
    const int* __restrict__ deg, const int4* __restrict__ ell4,
    float* __restrict__ out, int N)
{
    int wid  = threadIdx.x >> 6;
    int lane = threadIdx.x & 63;
    int hl = lane >> 5;          // half: 0 or 1
    int sl = lane & 31;          // sub-lane within half
    int node = blockIdx.x * 8 + wid * 2 + hl;
    if (node >= N) return;

    // independent loads up front
    float4 xv = *(const float4*)&X[(size_t)node * FDIM + sl * 4];
    int4 e0 = ell4[node * 2];        // slots 0..3 (same addr across 32 lanes: L1 broadcast)
    int4 e1 = ell4[node * 2 + 1];    // slots 4..7
    int d = deg[node];
    if (d > SLOTS) d = SLOTS;

    int slots[SLOTS] = { e0.x, e0.y, e0.z, e0.w, e1.x, e1.y, e1.z, e1.w };

    // burst: all <=8 Y-row loads in flight at once
    uint2 p[SLOTS];
    #pragma unroll
    for (int j = 0; j < SLOTS; ++j)
        if (j < d) p[j] = Yp[(size_t)slots[j] * (FDIM / 4) + sl];   // 8B/lane, 256B/edge

    float a0 = 0.f, a1 = 0.f, a2 = 0.f, a3 = 0.f;
    #pragma unroll
    for (int j = 0; j < SLOTS; ++j) {
        if (j < d) {
            a0 += bf_lo(p[j].x); a1 += bf_hi(p[j].x);
            a2 += bf_lo(p[j].y); a3 += bf_hi(p[j].y);
        }
    }
    float4 o = make_float4(xv.x + a0, xv.y + a1, xv.z + a2, xv.w + a3);
    *(float4*)&out[(size_t)node * FDIM + sl * 4] = o;
}

// ---- K4: replay overflow edges (deg > SLOTS) with f32 atomics; tiny count ----
__global__ __launch_bounds__(256) void ovf_kernel(
    const int2* __restrict__ ovf, const int* __restrict__ ovfcnt,
    const uint2* __restrict__ Yp, float* __restrict__ out)
{
    int cnt = *ovfcnt;
    if (cnt > OVFCAP) cnt = OVFCAP;
    int hw  = (blockIdx.x * 256 + threadIdx.x) >> 5;   // global half-wave id
    int sl  = threadIdx.x & 31;
    int nhw = gridDim.x * 8;
    for (int i = hw; i < cnt; i += nhw) {
        int2 ed = ovf[i];
        uint2 pv = Yp[(size_t)ed.x * (FDIM / 4) + sl];
        float* dst = out + (size_t)ed.y * FDIM + sl * 4;
        atomicAdd(dst + 0, bf_lo(pv.x));
        atomicAdd(dst + 1, bf_hi(pv.x));
        atomicAdd(dst + 2, bf_lo(pv.y));
        atomicAdd(dst + 3, bf_hi(pv.y));
    }
}

extern "C" void kernel_launch(void* const* d_in, const int* in_sizes, int n_in,
                              void* d_out, int out_size, void* d_ws, size_t ws_size,
                              hipStream_t stream) {
    const float* X  = (const float*)d_in[0];
    const float* Wg = (const float*)d_in[1];
    const float* bg = (const float*)d_in[2];
    const int*   lv = (const int*)d_in[3];
    const int*   eg = (const int*)d_in[4];
    float* out = (float*)d_out;

    int N = in_sizes[3];
    int E = in_sizes[4] / 2;

    // workspace: Y (bf16 N*F) | cnt(16: [0..3] level counts, [8] ovf counter)
    //            deg(N) [zeroed with cnt] | ell(8N) | bin(4N) | ovf(OVFCAP int2)
    char* p = (char*)d_ws;
    u16* Y     = (u16*)p;   p += (size_t)N * FDIM * sizeof(u16);
    int* cnt   = (int*)p;   p += 16 * sizeof(int);
    int* deg   = (int*)p;   p += (size_t)N * sizeof(int);
    int* ell   = (int*)p;   p += (size_t)SLOTS * N * sizeof(int);
    int* bin   = (int*)p;   p += (size_t)4 * N * sizeof(int);
    int2* ovf  = (int2*)p;
    int* ovfcnt = cnt + 8;

    int nzero4 = (N + 16) / 4;   // cnt(16) + deg(N), N divisible by 4
    zero_kernel<<<(nzero4 + 255) / 256, 256, 0, stream>>>((int4*)cnt, nzero4);

    int nodeBlocks = (N + 255) / 256;
    int edgeBlocks = (E + 255) / 256;
    fillbin_kernel<<<max(nodeBlocks, edgeBlocks), 256, 0, stream>>>(
        lv, cnt, bin, (const int2*)eg, deg, ell, ovf, ovfcnt, N, E, nodeBlocks);

    int blocksPerLevel = (N + NT - 1) / NT;
    transform_kernel<<<NLEV * blocksPerLevel, 256, 0, stream>>>(
        X, Wg, bg, cnt, bin, Y, N, blocksPerLevel);

    gather_kernel<<<(N + 7) / 8, 256, 0, stream>>>(
        X, (const uint2*)Y, deg, (const int4*)ell, out, N);

    ovf_kernel<<<64, 256, 0, stream>>>(ovf, ovfcnt, (const uint2*)Y, out);
}